// Round 4
// baseline (310.853 us; speedup 1.0000x reference)
//
#include <hip/hip_runtime.h>
#include <cstdint>
#include <cstddef>

#define DEV static __device__ __forceinline__

typedef __attribute__((ext_vector_type(8))) short bf16x8;   // 8 bf16 (4 VGPRs)
typedef __attribute__((ext_vector_type(4))) float f32x4;

constexpr int NB   = 64;     // batch
constexpr int NTOK = 197;    // tokens
constexpr int DIMC = 768;    // channels
constexpr int NH   = 12;     // heads
constexpr int HDIM = 64;     // head dim
constexpr int MTOK = NB * NTOK;   // 12608 rows
constexpr int QKVO = 3 * DIMC;    // 2304
constexpr int BH   = NB * NH;     // 768
constexpr int NPAD = 224;         // padded key count (7 x 32)
constexpr int HEADS_PER_BLK = 3;  // attn: 256 blocks x 3 heads

DEV unsigned short f2bf(float f) {
  union { float f; uint32_t u; } v; v.f = f;
  uint32_t u = v.u;
  return (unsigned short)((u + 0x7FFFu + ((u >> 16) & 1u)) >> 16);  // RNE, finite inputs
}

DEV uint32_t pack_bf2(float a, float b) {
  return (uint32_t)f2bf(a) | ((uint32_t)f2bf(b) << 16);
}

DEV f32x4 mfma16(bf16x8 a, bf16x8 b, f32x4 c) {
  return __builtin_amdgcn_mfma_f32_16x16x32_bf16(a, b, c, 0, 0, 0);
}

DEV void async_cp16(const unsigned short* g, unsigned short* l) {
  // direct global->LDS DMA, 16B/lane; LDS dest is lane-contiguous (no pad!)
  __builtin_amdgcn_global_load_lds(
      (__attribute__((address_space(1))) void*)g,
      (__attribute__((address_space(3))) void*)l, 16, 0, 0);
}

// supertile swizzle: groups of 8 M-tiles, N-major inside the group.
DEV void swizzle_mn(int lin, int gridM, int gridN, int& mbase, int& nbase) {
  int per = 8 * gridN;
  int sup = lin / per;
  int bm  = sup * 8;
  int Gm  = gridM - bm; if (Gm > 8) Gm = 8;
  int rem = lin - sup * per;
  int n   = rem / Gm;
  int mm  = rem - n * Gm;
  mbase = (bm + mm) * 128;
  nbase = n * 128;
}

// ---------------- f32 -> bf16 convert (memory-bound) ----------------
__global__ void __launch_bounds__(256) cvt_bf16(const float* __restrict__ s,
                                                unsigned short* __restrict__ d, int n) {
  int i = (blockIdx.x * 256 + threadIdx.x) * 4;
  if (i < n) {
    float4 f = *(const float4*)(s + i);
    ushort4 o;
    o.x = f2bf(f.x); o.y = f2bf(f.y); o.z = f2bf(f.z); o.w = f2bf(f.w);
    *(ushort4*)(d + i) = o;
  }
}

// ---------------- shared NT-GEMM main loop (m97 structure) ----------------
DEV void gemm_mainloop(const unsigned short* __restrict__ A, int Arows,
                       const unsigned short* __restrict__ Bw,
                       unsigned short* As, unsigned short* Bs,
                       int mbase, int nbase, f32x4 acc[4][4]) {
  const int tid  = threadIdx.x;
  const int lane = tid & 63;
  const int wave = tid >> 6;
  const int wm = wave & 1, wn = wave >> 1;
  const int l16 = lane & 15, quad = lane >> 4;

  for (int k0 = 0; k0 < DIMC; k0 += 64) {
#pragma unroll
    for (int i = 0; i < 4; ++i) {
      int c = i * 256 + tid;          // LDS chunk id 0..1023 (16B chunks)
      int row = c >> 3, cc = c & 7;
      int gc = (cc ^ (row & 7)) * 8;  // swizzled global chunk
      int ar = mbase + row; ar = ar < Arows ? ar : Arows - 1;  // M tail clamp
      async_cp16(A  + (size_t)ar * DIMC + k0 + gc, As + c * 8);
      async_cp16(Bw + (size_t)(nbase + row) * DIMC + k0 + gc, Bs + c * 8);
    }
    __syncthreads();
#pragma unroll
    for (int kk = 0; kk < 64; kk += 32) {
      const int cw = (kk >> 3) + quad;
      bf16x8 af[4], bfr[4];
#pragma unroll
      for (int mi = 0; mi < 4; ++mi) {
        int r = wm * 64 + mi * 16 + l16;
        af[mi] = *(const bf16x8*)(As + r * 64 + (cw ^ (r & 7)) * 8);
      }
#pragma unroll
      for (int ni = 0; ni < 4; ++ni) {
        int r = wn * 64 + ni * 16 + l16;
        bfr[ni] = *(const bf16x8*)(Bs + r * 64 + (cw ^ (r & 7)) * 8);
      }
#pragma unroll
      for (int mi = 0; mi < 4; ++mi)
#pragma unroll
        for (int ni = 0; ni < 4; ++ni)
          acc[mi][ni] = mfma16(af[mi], bfr[ni], acc[mi][ni]);
    }
    __syncthreads();
  }
}

// ---------------- QKV GEMM -> qkv bf16 [3][B][H][N][HD] (R2 epilogue) ----------------
__global__ void __launch_bounds__(256) gemm_qkv(const unsigned short* __restrict__ A,
                                                const unsigned short* __restrict__ Bw,
                                                unsigned short* __restrict__ qkv,
                                                int gridM, int gridN) {
  __shared__ __align__(16) unsigned short As[128 * 64];
  __shared__ __align__(16) unsigned short Bs[128 * 64];
  const int tid = threadIdx.x, lane = tid & 63, wave = tid >> 6;
  const int wm = wave & 1, wn = wave >> 1;
  const int l16 = lane & 15, quad = lane >> 4;
  int mbase, nbase;
  swizzle_mn(blockIdx.x, gridM, gridN, mbase, nbase);

  f32x4 acc[4][4];
#pragma unroll
  for (int i = 0; i < 4; ++i)
#pragma unroll
    for (int j = 0; j < 4; ++j) acc[i][j] = {0.f, 0.f, 0.f, 0.f};

  gemm_mainloop(A, MTOK, Bw, As, Bs, mbase, nbase, acc);

  const int oc64  = nbase + wn * 64;            // 64-aligned -> uniform which/h
  const int which = oc64 / DIMC;
  const int h     = (oc64 % DIMC) / HDIM;
#pragma unroll
  for (int mi = 0; mi < 4; ++mi) {
    int t0 = mbase + wm * 64 + mi * 16 + quad * 4;
#pragma unroll
    for (int r = 0; r < 4; ++r) {
      int t = t0 + r;
      if (t < MTOK) {
        int b = t / NTOK, n = t - b * NTOK;
        size_t base = ((size_t)((which * NB + b) * NH + h) * NTOK + n) * HDIM;
#pragma unroll
        for (int ni = 0; ni < 4; ++ni)
          qkv[base + ni * 16 + l16] = f2bf(acc[mi][ni][r]);
      }
    }
  }
}

// ---------------- Proj GEMM + bias + residual (fp32 out) ----------------
__global__ void __launch_bounds__(256) gemm_proj(const unsigned short* __restrict__ A,
                                                 const unsigned short* __restrict__ Bw,
                                                 const float* __restrict__ bias,
                                                 const float* __restrict__ xres,
                                                 float* __restrict__ out,
                                                 int gridM, int gridN) {
  __shared__ __align__(16) unsigned short As[128 * 64];
  __shared__ __align__(16) unsigned short Bs[128 * 64];
  const int tid = threadIdx.x, lane = tid & 63, wave = tid >> 6;
  const int wm = wave & 1, wn = wave >> 1;
  const int l16 = lane & 15, quad = lane >> 4;
  int mbase, nbase;
  swizzle_mn(blockIdx.x, gridM, gridN, mbase, nbase);

  f32x4 acc[4][4];
#pragma unroll
  for (int i = 0; i < 4; ++i)
#pragma unroll
    for (int j = 0; j < 4; ++j) acc[i][j] = {0.f, 0.f, 0.f, 0.f};

  gemm_mainloop(A, MTOK, Bw, As, Bs, mbase, nbase, acc);

  const int oc = nbase + wn * 64;
#pragma unroll
  for (int mi = 0; mi < 4; ++mi) {
    int t0 = mbase + wm * 64 + mi * 16 + quad * 4;
#pragma unroll
    for (int r = 0; r < 4; ++r) {
      int t = t0 + r;
      if (t < MTOK) {
        size_t rowb = (size_t)t * DIMC;
#pragma unroll
        for (int ni = 0; ni < 4; ++ni) {
          int o = oc + ni * 16 + l16;
          out[rowb + o] = acc[mi][ni][r] + bias[o] + xres[rowb + o];
        }
      }
    }
  }
}

// ---------------- fused attention: 256 blocks x 3 heads, pipelined ----------------
// Double-buffered K staging via global_load_lds: head i+1's DMAs issue before
// head i's compute, so the end-of-iteration barrier drain overlaps ~a full
// head of compute. S^T = K.Q^T from LDS; softmax per lane (q=l16, 2 shfls);
// inv folded into P; O = P.V with A = P via shfl, B = V column loads (L1-hot).
__global__ void __launch_bounds__(256, 2) attn_fused(const unsigned short* __restrict__ qkv,
                                                     const float* __restrict__ scale,
                                                     unsigned short* __restrict__ aout) {
  __shared__ __align__(16) unsigned short Ks[2][NPAD * 64];   // 2 x 28672 B

  const int tid = threadIdx.x, lane = tid & 63, wave = tid >> 6;
  const int l16 = lane & 15, quad = lane >> 4;
  const int bh0 = blockIdx.x * HEADS_PER_BLK;

  const unsigned short* kg0 = qkv + (size_t)BH * (NTOK * HDIM);
  const unsigned short* vg0 = qkv + (size_t)2 * BH * (NTOK * HDIM);

  // stage head 0's K (rows >=197 overread valid neighboring memory; masked)
  {
    const unsigned short* kg = kg0 + (size_t)bh0 * (NTOK * HDIM);
#pragma unroll
    for (int i = 0; i < 7; ++i) {
      int c = i * 256 + tid;
      int row = c >> 3, cc = c & 7;
      async_cp16(kg + (size_t)row * 64 + ((cc ^ (row & 7)) * 8), Ks[0] + c * 8);
    }
  }
  __syncthreads();

  // P-exchange lanes: A[m=q=l16][k=quad*8+j]; sources hold keys quad'*4+r
  const int aSrc  = l16 + ((quad & 1) << 5);   // quad' = 2*(quad&1)
  const int bSrc  = aSrc + 16;                 // quad' = 2*(quad&1)+1
  const int stsel = quad >> 1;                 // key>=16 -> st=1

  for (int it = 0; it < HEADS_PER_BLK; ++it) {
    const int bh = bh0 + it;
    const int b = bh / NH, h = bh - b * NH;
    const unsigned short* qg = qkv + (size_t)bh * (NTOK * HDIM);
    const unsigned short* vg = vg0 + (size_t)bh * (NTOK * HDIM);
    const unsigned short* ks = Ks[it & 1];
    const float sc = scale[h];

    // pipeline: issue next head's K DMAs now; they land during this compute
    if (it + 1 < HEADS_PER_BLK) {
      const unsigned short* kg = kg0 + (size_t)(bh + 1) * (NTOK * HDIM);
      unsigned short* dst = Ks[(it + 1) & 1];
#pragma unroll
      for (int i = 0; i < 7; ++i) {
        int c = i * 256 + tid;
        int row = c >> 3, cc = c & 7;
        async_cp16(kg + (size_t)row * 64 + ((cc ^ (row & 7)) * 8), dst + c * 8);
      }
    }

    for (int mt = wave; mt < 13; mt += 4) {   // Q 16-row tiles, round-robin
      int qr = mt * 16 + l16; if (qr > NTOK - 1) qr = NTOK - 1;   // clamp tail
      bf16x8 qb0 = *(const bf16x8*)(qg + (size_t)qr * 64 + quad * 8);
      bf16x8 qb1 = *(const bf16x8*)(qg + (size_t)qr * 64 + 32 + quad * 8);
      const int mg = mt * 16 + l16;           // global Q row (diag mask)

      // ---- batched S^T = K.Q^T: 28 independent MFMAs, K from LDS ----
      f32x4 s[7][2];
#pragma unroll
      for (int jc = 0; jc < 7; ++jc)
#pragma unroll
        for (int st = 0; st < 2; ++st) {
          int jrow = (jc * 2 + st) * 16 + l16;
          const unsigned short* kr = ks + jrow * 64;
          bf16x8 ka0 = *(const bf16x8*)(kr + (quad       ^ (jrow & 7)) * 8);
          bf16x8 ka1 = *(const bf16x8*)(kr + ((4 + quad) ^ (jrow & 7)) * 8);
          f32x4 t = {0.f, 0.f, 0.f, 0.f};
          t = mfma16(ka0, qb0, t);
          t = mfma16(ka1, qb1, t);
          s[jc][st] = t;
        }

      // ---- softmax (per lane: q = l16): scale+mask, max, exp, sum ----
      float cmax = -1e30f;
#pragma unroll
      for (int jc = 0; jc < 7; ++jc)
#pragma unroll
        for (int st = 0; st < 2; ++st)
#pragma unroll
          for (int r = 0; r < 4; ++r) {
            int jg = jc * 32 + st * 16 + quad * 4 + r;
            float v = s[jc][st][r] * sc;
            v = (jg >= NTOK || jg == mg) ? -1e30f : v;   // select: NaN-safe
            s[jc][st][r] = v;
            cmax = fmaxf(cmax, v);
          }
      cmax = fmaxf(cmax, __shfl_xor(cmax, 16));
      cmax = fmaxf(cmax, __shfl_xor(cmax, 32));
      float psum = 0.f;
#pragma unroll
      for (int jc = 0; jc < 7; ++jc)
#pragma unroll
        for (int st = 0; st < 2; ++st)
#pragma unroll
          for (int r = 0; r < 4; ++r) {
            float e = __expf(s[jc][st][r] - cmax);
            psum += e;
            s[jc][st][r] = e;
          }
      psum += __shfl_xor(psum, 16);
      psum += __shfl_xor(psum, 32);
      const float inv = 1.0f / psum;           // q = l16; fold into P now

      // ---- O = P.V: A = P via shfl (normalized), B = V column loads ----
      f32x4 oacc[4];
#pragma unroll
      for (int dt = 0; dt < 4; ++dt) oacc[dt] = {0.f, 0.f, 0.f, 0.f};

#pragma unroll
      for (int jc = 0; jc < 7; ++jc) {
        uint32_t u0 = pack_bf2(s[jc][0][0] * inv, s[jc][0][1] * inv);
        uint32_t v0 = pack_bf2(s[jc][0][2] * inv, s[jc][0][3] * inv);
        uint32_t u1 = pack_bf2(s[jc][1][0] * inv, s[jc][1][1] * inv);
        uint32_t v1 = pack_bf2(s[jc][1][2] * inv, s[jc][1][3] * inv);
        uint32_t au0 = (uint32_t)__shfl((int)u0, aSrc);
        uint32_t av0 = (uint32_t)__shfl((int)v0, aSrc);
        uint32_t au1 = (uint32_t)__shfl((int)u1, aSrc);
        uint32_t av1 = (uint32_t)__shfl((int)v1, aSrc);
        uint32_t bu0 = (uint32_t)__shfl((int)u0, bSrc);
        uint32_t bv0 = (uint32_t)__shfl((int)v0, bSrc);
        uint32_t bu1 = (uint32_t)__shfl((int)u1, bSrc);
        uint32_t bv1 = (uint32_t)__shfl((int)v1, bSrc);
        union { uint32_t u[4]; bf16x8 v; } pa;
        pa.u[0] = stsel ? au1 : au0;     // keys j=0,1
        pa.u[1] = stsel ? av1 : av0;     // keys j=2,3
        pa.u[2] = stsel ? bu1 : bu0;     // keys j=4,5
        pa.u[3] = stsel ? bv1 : bv0;     // keys j=6,7
#pragma unroll
        for (int dt = 0; dt < 4; ++dt) {
          // B[k=quad*8+j][n=l16] = V[key][d=dt*16+l16]: 8 column loads
          union { unsigned short us[8]; bf16x8 v; } vb;
          const unsigned short* vp = vg + (size_t)(jc * 32 + quad * 8) * 64 +
                                     dt * 16 + l16;
#pragma unroll
          for (int j = 0; j < 8; ++j) vb.us[j] = vp[j * 64];
          oacc[dt] = mfma16(pa.v, vb.v, oacc[dt]);
        }
      }

      // ---- store O: lane holds q=quad*4+r (rows), d=dt*16+l16 (col) ----
#pragma unroll
      for (int r = 0; r < 4; ++r) {
        int qrow = mt * 16 + quad * 4 + r;
        if (qrow < NTOK) {
          size_t ob = (size_t)(b * NTOK + qrow) * DIMC + h * HDIM;
#pragma unroll
          for (int dt = 0; dt < 4; ++dt)
            aout[ob + dt * 16 + l16] = f2bf(oacc[dt][r]);
        }
      }
    }
    __syncthreads();   // drains next head's DMAs (overlapped) + buf reuse
  }
}

// ---------------- launcher ----------------
extern "C" void kernel_launch(void* const* d_in, const int* in_sizes, int n_in,
                              void* d_out, int out_size, void* d_ws, size_t ws_size,
                              hipStream_t stream) {
  const float* x     = (const float*)d_in[0];
  const float* scale = (const float*)d_in[1];
  const float* wqkv  = (const float*)d_in[2];
  const float* wproj = (const float*)d_in[3];
  const float* bproj = (const float*)d_in[4];
  float* out = (float*)d_out;

  // ws layout (ushort), ~82.2 MB total (R1/R2 proven footprint).
  // attb aliases xb (dead after gemm_qkv; proj residual reads fp32 x).
  unsigned short* xb   = (unsigned short*)d_ws;
  unsigned short* wqb  = xb  + (size_t)MTOK * DIMC;
  unsigned short* wpb  = wqb + (size_t)QKVO * DIMC;
  unsigned short* qkvb = wpb + (size_t)DIMC * DIMC;
  unsigned short* attb = xb;                          // alias

  cvt_bf16<<<(MTOK * DIMC) / 1024, 256, 0, stream>>>(x, xb, MTOK * DIMC);
  cvt_bf16<<<(QKVO * DIMC) / 1024, 256, 0, stream>>>(wqkv, wqb, QKVO * DIMC);
  cvt_bf16<<<(DIMC * DIMC) / 1024, 256, 0, stream>>>(wproj, wpb, DIMC * DIMC);

  const int gmM = (MTOK + 127) / 128;      // 99
  gemm_qkv<<<gmM * (QKVO / 128), 256, 0, stream>>>(xb, wqb, qkvb, gmM, QKVO / 128);
  attn_fused<<<BH / HEADS_PER_BLK, 256, 0, stream>>>(qkvb, scale, attb);
  gemm_proj<<<gmM * (DIMC / 128), 256, 0, stream>>>(attb, wpb, bproj, x, out,
                                                    gmM, DIMC / 128);
}

// Round 5
// 248.144 us; speedup vs baseline: 1.2527x; 1.2527x over previous
//
#include <hip/hip_runtime.h>
#include <cstdint>
#include <cstddef>

#define DEV static __device__ __forceinline__

typedef __attribute__((ext_vector_type(8))) short bf16x8;   // 8 bf16 (4 VGPRs)
typedef __attribute__((ext_vector_type(4))) float f32x4;

constexpr int NB   = 64;     // batch
constexpr int NTOK = 197;    // tokens
constexpr int DIMC = 768;    // channels
constexpr int NH   = 12;     // heads
constexpr int HDIM = 64;     // head dim
constexpr int MTOK = NB * NTOK;   // 12608 rows
constexpr int QKVO = 3 * DIMC;    // 2304
constexpr int BH   = NB * NH;     // 768
constexpr int KROWS = 208;        // staged K rows (max jrow = 207)
constexpr int NPAD  = 224;        // padded key count (7 x 32)
constexpr int OBS   = 72;         // O-bounce row stride (ushorts)
constexpr int HEADS_PER_BLK = 3;  // attn: 256 blocks x 3 heads

DEV unsigned short f2bf(float f) {
  union { float f; uint32_t u; } v; v.f = f;
  uint32_t u = v.u;
  return (unsigned short)((u + 0x7FFFu + ((u >> 16) & 1u)) >> 16);  // RNE, finite inputs
}

DEV uint32_t pack_bf2(float a, float b) {
  return (uint32_t)f2bf(a) | ((uint32_t)f2bf(b) << 16);
}

DEV f32x4 mfma16(bf16x8 a, bf16x8 b, f32x4 c) {
  return __builtin_amdgcn_mfma_f32_16x16x32_bf16(a, b, c, 0, 0, 0);
}

DEV void async_cp16(const unsigned short* g, unsigned short* l) {
  // direct global->LDS DMA, 16B/lane; LDS dest is lane-contiguous (no pad!)
  __builtin_amdgcn_global_load_lds(
      (__attribute__((address_space(1))) void*)g,
      (__attribute__((address_space(3))) void*)l, 16, 0, 0);
}

// supertile swizzle: groups of 8 M-tiles, N-major inside the group.
DEV void swizzle_mn(int lin, int gridM, int gridN, int& mbase, int& nbase) {
  int per = 8 * gridN;
  int sup = lin / per;
  int bm  = sup * 8;
  int Gm  = gridM - bm; if (Gm > 8) Gm = 8;
  int rem = lin - sup * per;
  int n   = rem / Gm;
  int mm  = rem - n * Gm;
  mbase = (bm + mm) * 128;
  nbase = n * 128;
}

// ---------------- f32 -> bf16 convert (memory-bound) ----------------
__global__ void __launch_bounds__(256) cvt_bf16(const float* __restrict__ s,
                                                unsigned short* __restrict__ d, int n) {
  int i = (blockIdx.x * 256 + threadIdx.x) * 4;
  if (i < n) {
    float4 f = *(const float4*)(s + i);
    ushort4 o;
    o.x = f2bf(f.x); o.y = f2bf(f.y); o.z = f2bf(f.z); o.w = f2bf(f.w);
    *(ushort4*)(d + i) = o;
  }
}

// ---------------- shared NT-GEMM main loop (m97 structure) ----------------
DEV void gemm_mainloop(const unsigned short* __restrict__ A, int Arows,
                       const unsigned short* __restrict__ Bw,
                       unsigned short* As, unsigned short* Bs,
                       int mbase, int nbase, f32x4 acc[4][4]) {
  const int tid  = threadIdx.x;
  const int lane = tid & 63;
  const int wave = tid >> 6;
  const int wm = wave & 1, wn = wave >> 1;
  const int l16 = lane & 15, quad = lane >> 4;

  for (int k0 = 0; k0 < DIMC; k0 += 64) {
#pragma unroll
    for (int i = 0; i < 4; ++i) {
      int c = i * 256 + tid;          // LDS chunk id 0..1023 (16B chunks)
      int row = c >> 3, cc = c & 7;
      int gc = (cc ^ (row & 7)) * 8;  // swizzled global chunk
      int ar = mbase + row; ar = ar < Arows ? ar : Arows - 1;  // M tail clamp
      async_cp16(A  + (size_t)ar * DIMC + k0 + gc, As + c * 8);
      async_cp16(Bw + (size_t)(nbase + row) * DIMC + k0 + gc, Bs + c * 8);
    }
    __syncthreads();
#pragma unroll
    for (int kk = 0; kk < 64; kk += 32) {
      const int cw = (kk >> 3) + quad;
      bf16x8 af[4], bfr[4];
#pragma unroll
      for (int mi = 0; mi < 4; ++mi) {
        int r = wm * 64 + mi * 16 + l16;
        af[mi] = *(const bf16x8*)(As + r * 64 + (cw ^ (r & 7)) * 8);
      }
#pragma unroll
      for (int ni = 0; ni < 4; ++ni) {
        int r = wn * 64 + ni * 16 + l16;
        bfr[ni] = *(const bf16x8*)(Bs + r * 64 + (cw ^ (r & 7)) * 8);
      }
#pragma unroll
      for (int mi = 0; mi < 4; ++mi)
#pragma unroll
        for (int ni = 0; ni < 4; ++ni)
          acc[mi][ni] = mfma16(af[mi], bfr[ni], acc[mi][ni]);
    }
    __syncthreads();
  }
}

// ---------------- QKV GEMM -> qkv bf16 [3][B][H][N][HD] ----------------
__global__ void __launch_bounds__(256) gemm_qkv(const unsigned short* __restrict__ A,
                                                const unsigned short* __restrict__ Bw,
                                                unsigned short* __restrict__ qkv,
                                                int gridM, int gridN) {
  __shared__ __align__(16) unsigned short As[128 * 64];
  __shared__ __align__(16) unsigned short Bs[128 * 64];
  const int tid = threadIdx.x, lane = tid & 63, wave = tid >> 6;
  const int wm = wave & 1, wn = wave >> 1;
  const int l16 = lane & 15, quad = lane >> 4;
  int mbase, nbase;
  swizzle_mn(blockIdx.x, gridM, gridN, mbase, nbase);

  f32x4 acc[4][4];
#pragma unroll
  for (int i = 0; i < 4; ++i)
#pragma unroll
    for (int j = 0; j < 4; ++j) acc[i][j] = {0.f, 0.f, 0.f, 0.f};

  gemm_mainloop(A, MTOK, Bw, As, Bs, mbase, nbase, acc);

  const int oc64  = nbase + wn * 64;            // 64-aligned -> uniform which/h
  const int which = oc64 / DIMC;
  const int h     = (oc64 % DIMC) / HDIM;
#pragma unroll
  for (int mi = 0; mi < 4; ++mi) {
    int t0 = mbase + wm * 64 + mi * 16 + quad * 4;
#pragma unroll
    for (int r = 0; r < 4; ++r) {
      int t = t0 + r;
      if (t < MTOK) {
        int b = t / NTOK, n = t - b * NTOK;
        size_t base = ((size_t)((which * NB + b) * NH + h) * NTOK + n) * HDIM;
#pragma unroll
        for (int ni = 0; ni < 4; ++ni)
          qkv[base + ni * 16 + l16] = f2bf(acc[mi][ni][r]);
      }
    }
  }
}

// ---------------- Proj GEMM + bias + residual (fp32 out) ----------------
__global__ void __launch_bounds__(256) gemm_proj(const unsigned short* __restrict__ A,
                                                 const unsigned short* __restrict__ Bw,
                                                 const float* __restrict__ bias,
                                                 const float* __restrict__ xres,
                                                 float* __restrict__ out,
                                                 int gridM, int gridN) {
  __shared__ __align__(16) unsigned short As[128 * 64];
  __shared__ __align__(16) unsigned short Bs[128 * 64];
  const int tid = threadIdx.x, lane = tid & 63, wave = tid >> 6;
  const int wm = wave & 1, wn = wave >> 1;
  const int l16 = lane & 15, quad = lane >> 4;
  int mbase, nbase;
  swizzle_mn(blockIdx.x, gridM, gridN, mbase, nbase);

  f32x4 acc[4][4];
#pragma unroll
  for (int i = 0; i < 4; ++i)
#pragma unroll
    for (int j = 0; j < 4; ++j) acc[i][j] = {0.f, 0.f, 0.f, 0.f};

  gemm_mainloop(A, MTOK, Bw, As, Bs, mbase, nbase, acc);

  const int oc = nbase + wn * 64;
#pragma unroll
  for (int mi = 0; mi < 4; ++mi) {
    int t0 = mbase + wm * 64 + mi * 16 + quad * 4;
#pragma unroll
    for (int r = 0; r < 4; ++r) {
      int t = t0 + r;
      if (t < MTOK) {
        size_t rowb = (size_t)t * DIMC;
#pragma unroll
        for (int ni = 0; ni < 4; ++ni) {
          int o = oc + ni * 16 + l16;
          out[rowb + o] = acc[mi][ni][r] + bias[o] + xres[rowb + o];
        }
      }
    }
  }
}

// ---------------- fused attention: 256 blocks x 3 heads ----------------
// Per head: K staged via async DMA into LDS (XOR-swizzled); V^T built in LDS
// via coalesced row reads (one 128B line per instr) + ds_write_b128 (7+7
// wave-instrs total). S^T = K.Q^T from LDS; softmax per lane (q=l16);
// P^T B-frags via shfl; O^T = V^T.P^T with A-frags as b128 LDS reads;
// O stored through a per-wave LDS bounce so every global store instruction
// writes full 128B lines (kills the 4x write amplification seen in R3/R4).
__global__ void __launch_bounds__(256, 2) attn_fused(const unsigned short* __restrict__ qkv,
                                                     const float* __restrict__ scale,
                                                     unsigned short* __restrict__ aout) {
  __shared__ __align__(16) unsigned short Ks[KROWS * 64];        // 26624 B
  __shared__ __align__(16) unsigned short Vt[HDIM * NPAD];       // 28672 B
  __shared__ __align__(16) unsigned short Ob[4 * 16 * OBS];      //  9216 B
  // total 64512 B

  const int tid = threadIdx.x, lane = tid & 63, wave = tid >> 6;
  const int l16 = lane & 15, quad = lane >> 4;
  const int bh0 = blockIdx.x * HEADS_PER_BLK;

  const unsigned short* kg0 = qkv + (size_t)BH * (NTOK * HDIM);
  const unsigned short* vg0 = qkv + (size_t)2 * BH * (NTOK * HDIM);

  // P-exchange lanes (R3-proven): B-frag P^T[k=quad*8+j][n=q=l16]
  const int srcA  = l16 + ((quad & 1) << 5);
  const int srcB  = srcA + 16;
  const int stsel = quad >> 1;

  unsigned short* ob = Ob + wave * (16 * OBS);

  for (int it = 0; it < HEADS_PER_BLK; ++it) {
    const int bh = bh0 + it;
    const int b = bh / NH, h = bh - b * NH;
    const unsigned short* qg = qkv + (size_t)bh * (NTOK * HDIM);
    const unsigned short* kg = kg0 + (size_t)bh * (NTOK * HDIM);
    const unsigned short* vg = vg0 + (size_t)bh * (NTOK * HDIM);
    const float sc = scale[h];

    // ---- stage K via DMA (rows 0..207; rows>=197 garbage, masked) ----
#pragma unroll
    for (int i = 0; i < 7; ++i) {
      int c = i * 256 + tid;                 // 16B chunk id, 1664 total
      if (c < KROWS * 8) {
        int row = c >> 3, cc = c & 7;
        async_cp16(kg + (size_t)row * 64 + ((cc ^ (row & 7)) * 8), Ks + c * 8);
      }
    }
    // ---- build V^T: coalesced row reads + one b128 LDS write per pass ----
    {
      const int dcol = tid & 63;             // this thread's V column
      const int slab = tid >> 6;             // wave -> 8-row slab
#pragma unroll
      for (int p = 0; p < 7; ++p) {
        int n0 = p * 32 + slab * 8;
        union { unsigned short us[8]; bf16x8 v; } tr;
#pragma unroll
        for (int i = 0; i < 8; ++i) {
          int n = n0 + i; n = n > NTOK - 1 ? NTOK - 1 : n;   // clamp (masked)
          tr.us[i] = vg[(size_t)n * HDIM + dcol];            // 128B line/instr
        }
        *(bf16x8*)(Vt + dcol * NPAD + n0) = tr.v;
      }
    }
    __syncthreads();   // drains DMA vmcnt + Vt lgkm

    for (int mt = wave; mt < 13; mt += 4) {   // Q 16-row tiles, round-robin
      int qr = mt * 16 + l16; if (qr > NTOK - 1) qr = NTOK - 1;
      bf16x8 qb0 = *(const bf16x8*)(qg + (size_t)qr * 64 + quad * 8);
      bf16x8 qb1 = *(const bf16x8*)(qg + (size_t)qr * 64 + 32 + quad * 8);
      const int mg = mt * 16 + l16;           // global Q row (diag mask)

      // ---- batched S^T = K.Q^T (26 MFMAs; jc=6,st=1 keys all masked) ----
      f32x4 s[7][2];
#pragma unroll
      for (int jc = 0; jc < 7; ++jc)
#pragma unroll
        for (int st = 0; st < 2; ++st) {
          if (jc == 6 && st == 1) { s[6][1] = {0.f, 0.f, 0.f, 0.f}; continue; }
          int jrow = (jc * 2 + st) * 16 + l16;     // <= 207
          const unsigned short* kr = Ks + jrow * 64;
          bf16x8 ka0 = *(const bf16x8*)(kr + (quad       ^ (jrow & 7)) * 8);
          bf16x8 ka1 = *(const bf16x8*)(kr + ((4 + quad) ^ (jrow & 7)) * 8);
          f32x4 t = {0.f, 0.f, 0.f, 0.f};
          t = mfma16(ka0, qb0, t);
          t = mfma16(ka1, qb1, t);
          s[jc][st] = t;
        }

      // ---- softmax over keys (row = l16): scale+mask, max, exp, sum ----
      float cmax = -1e30f;
#pragma unroll
      for (int jc = 0; jc < 7; ++jc)
#pragma unroll
        for (int st = 0; st < 2; ++st)
#pragma unroll
          for (int r = 0; r < 4; ++r) {
            int jg = jc * 32 + st * 16 + quad * 4 + r;
            float v = s[jc][st][r] * sc;
            v = (jg >= NTOK || jg == mg) ? -1e30f : v;   // select: NaN-safe
            s[jc][st][r] = v;
            cmax = fmaxf(cmax, v);
          }
      cmax = fmaxf(cmax, __shfl_xor(cmax, 16));
      cmax = fmaxf(cmax, __shfl_xor(cmax, 32));
      float psum = 0.f;
#pragma unroll
      for (int jc = 0; jc < 7; ++jc)
#pragma unroll
        for (int st = 0; st < 2; ++st)
#pragma unroll
          for (int r = 0; r < 4; ++r) {
            float e = __expf(s[jc][st][r] - cmax);
            psum += e;
            s[jc][st][r] = e;
          }
      psum += __shfl_xor(psum, 16);
      psum += __shfl_xor(psum, 32);
      const float inv = 1.0f / psum;

      // ---- PV: O^T = V^T.P^T; P^T B-frags via shfl, V^T b128 from LDS ----
      f32x4 oacc[4];
#pragma unroll
      for (int dt = 0; dt < 4; ++dt) oacc[dt] = {0.f, 0.f, 0.f, 0.f};

#pragma unroll
      for (int jc = 0; jc < 7; ++jc) {
        uint32_t u0 = pack_bf2(s[jc][0][0], s[jc][0][1]);
        uint32_t v0 = pack_bf2(s[jc][0][2], s[jc][0][3]);
        uint32_t u1 = pack_bf2(s[jc][1][0], s[jc][1][1]);
        uint32_t v1 = pack_bf2(s[jc][1][2], s[jc][1][3]);
        uint32_t au0 = (uint32_t)__shfl((int)u0, srcA);
        uint32_t av0 = (uint32_t)__shfl((int)v0, srcA);
        uint32_t au1 = (uint32_t)__shfl((int)u1, srcA);
        uint32_t av1 = (uint32_t)__shfl((int)v1, srcA);
        uint32_t bu0 = (uint32_t)__shfl((int)u0, srcB);
        uint32_t bv0 = (uint32_t)__shfl((int)v0, srcB);
        uint32_t bu1 = (uint32_t)__shfl((int)u1, srcB);
        uint32_t bv1 = (uint32_t)__shfl((int)v1, srcB);
        union { uint32_t u[4]; bf16x8 v; } pb;
        pb.u[0] = stsel ? au1 : au0;
        pb.u[1] = stsel ? av1 : av0;
        pb.u[2] = stsel ? bu1 : bu0;
        pb.u[3] = stsel ? bv1 : bv0;
#pragma unroll
        for (int dt = 0; dt < 4; ++dt) {
          bf16x8 va = *(const bf16x8*)(Vt + (dt * 16 + l16) * NPAD +
                                       jc * 32 + quad * 8);
          oacc[dt] = mfma16(va, pb.v, oacc[dt]);
        }
      }

      // ---- O store via per-wave LDS bounce -> full 128B line stores ----
      // O^T C-layout: lane holds q=l16, d = dt*16 + quad*4 + r
#pragma unroll
      for (int dt = 0; dt < 4; ++dt) {
        ushort4 pk;
        pk.x = f2bf(oacc[dt][0] * inv);
        pk.y = f2bf(oacc[dt][1] * inv);
        pk.z = f2bf(oacc[dt][2] * inv);
        pk.w = f2bf(oacc[dt][3] * inv);
        *(ushort4*)(ob + l16 * OBS + dt * 16 + quad * 4) = pk;
      }
      __asm__ __volatile__("s_waitcnt lgkmcnt(0)" ::: "memory");
#pragma unroll
      for (int rnd = 0; rnd < 4; ++rnd) {
        int q   = rnd * 4 + (lane >> 4);     // 0..15
        int o8  = lane & 15;                 // 8B unit within the 128B row
        uint2 d8 = *(const uint2*)(ob + q * OBS + o8 * 4);
        int qrow = mt * 16 + q;
        if (qrow < NTOK) {
          size_t obase = (size_t)(b * NTOK + qrow) * DIMC + h * HDIM;
          *(uint2*)(aout + obase + o8 * 4) = d8;   // 16 lanes = full 128B line
        }
      }
    }
    __syncthreads();   // all tiles done before next head overwrites Ks/Vt
  }
}

// ---------------- launcher ----------------
extern "C" void kernel_launch(void* const* d_in, const int* in_sizes, int n_in,
                              void* d_out, int out_size, void* d_ws, size_t ws_size,
                              hipStream_t stream) {
  const float* x     = (const float*)d_in[0];
  const float* scale = (const float*)d_in[1];
  const float* wqkv  = (const float*)d_in[2];
  const float* wproj = (const float*)d_in[3];
  const float* bproj = (const float*)d_in[4];
  float* out = (float*)d_out;

  // ws layout (ushort), ~82.2 MB. attb aliases xb (dead after gemm_qkv;
  // proj residual reads fp32 x).
  unsigned short* xb   = (unsigned short*)d_ws;
  unsigned short* wqb  = xb  + (size_t)MTOK * DIMC;
  unsigned short* wpb  = wqb + (size_t)QKVO * DIMC;
  unsigned short* qkvb = wpb + (size_t)DIMC * DIMC;
  unsigned short* attb = xb;                          // alias

  cvt_bf16<<<(MTOK * DIMC) / 1024, 256, 0, stream>>>(x, xb, MTOK * DIMC);
  cvt_bf16<<<(QKVO * DIMC) / 1024, 256, 0, stream>>>(wqkv, wqb, QKVO * DIMC);
  cvt_bf16<<<(DIMC * DIMC) / 1024, 256, 0, stream>>>(wproj, wpb, DIMC * DIMC);

  const int gmM = (MTOK + 127) / 128;      // 99
  gemm_qkv<<<gmM * (QKVO / 128), 256, 0, stream>>>(xb, wqb, qkvb, gmM, QKVO / 128);
  attn_fused<<<BH / HEADS_PER_BLK, 256, 0, stream>>>(qkvb, scale, attb);
  gemm_proj<<<gmM * (DIMC / 128), 256, 0, stream>>>(attb, wpb, bproj, x, out,
                                                    gmM, DIMC / 128);
}

// Round 6
// 232.490 us; speedup vs baseline: 1.3371x; 1.0673x over previous
//
#include <hip/hip_runtime.h>
#include <cstdint>
#include <cstddef>

#define DEV static __device__ __forceinline__

typedef __attribute__((ext_vector_type(8))) short bf16x8;   // 8 bf16 (4 VGPRs)
typedef __attribute__((ext_vector_type(4))) float f32x4;

constexpr int NB   = 64;     // batch
constexpr int NTOK = 197;    // tokens
constexpr int DIMC = 768;    // channels
constexpr int NH   = 12;     // heads
constexpr int HDIM = 64;     // head dim
constexpr int MTOK = NB * NTOK;   // 12608 rows
constexpr int QKVO = 3 * DIMC;    // 2304
constexpr int BH   = NB * NH;     // 768
constexpr int KROWS = 198;        // staged K rows (jrow clamped to 197)
constexpr int VTS   = 232;        // V^T row stride (464B = 29x16B: bank-walking)
constexpr int OBS   = 68;         // O-bounce row stride (136B, 8B-aligned)

DEV unsigned short f2bf(float f) {
  union { float f; uint32_t u; } v; v.f = f;
  uint32_t u = v.u;
  return (unsigned short)((u + 0x7FFFu + ((u >> 16) & 1u)) >> 16);  // RNE, finite inputs
}

DEV uint32_t pack_bf2(float a, float b) {
  return (uint32_t)f2bf(a) | ((uint32_t)f2bf(b) << 16);
}

DEV f32x4 mfma16(bf16x8 a, bf16x8 b, f32x4 c) {
  return __builtin_amdgcn_mfma_f32_16x16x32_bf16(a, b, c, 0, 0, 0);
}

DEV void async_cp16(const unsigned short* g, unsigned short* l) {
  // direct global->LDS DMA, 16B/lane; LDS dest is lane-contiguous (no pad!)
  __builtin_amdgcn_global_load_lds(
      (__attribute__((address_space(1))) void*)g,
      (__attribute__((address_space(3))) void*)l, 16, 0, 0);
}

// supertile swizzle: groups of 8 M-tiles, N-major inside the group.
DEV void swizzle_mn(int lin, int gridM, int gridN, int& mbase, int& nbase) {
  int per = 8 * gridN;
  int sup = lin / per;
  int bm  = sup * 8;
  int Gm  = gridM - bm; if (Gm > 8) Gm = 8;
  int rem = lin - sup * per;
  int n   = rem / Gm;
  int mm  = rem - n * Gm;
  mbase = (bm + mm) * 128;
  nbase = n * 128;
}

// ---------------- fused f32 -> bf16 converts (one launch, 3 segments) ----------------
constexpr int CVT_E1 = MTOK * DIMC;       // 9,682,944  (exactly 9456*1024)
constexpr int CVT_E2 = QKVO * DIMC;       // 1,769,472  (exactly 1728*1024)
constexpr int CVT_E3 = DIMC * DIMC;       //   589,824  (exactly  576*1024)
constexpr int CVT_B1 = CVT_E1 / 1024;
constexpr int CVT_B2 = CVT_E2 / 1024;
constexpr int CVT_B3 = CVT_E3 / 1024;

__global__ void __launch_bounds__(256) cvt_all(const float* __restrict__ x,
                                               const float* __restrict__ wq,
                                               const float* __restrict__ wp,
                                               unsigned short* __restrict__ xb,
                                               unsigned short* __restrict__ wqb,
                                               unsigned short* __restrict__ wpb) {
  int blk = blockIdx.x;
  const float* s; unsigned short* d;
  if (blk < CVT_B1)                { s = x;  d = xb; }
  else if (blk < CVT_B1 + CVT_B2)  { s = wq; d = wqb; blk -= CVT_B1; }
  else                             { s = wp; d = wpb; blk -= CVT_B1 + CVT_B2; }
  int i = (blk * 256 + threadIdx.x) * 4;   // all segments are exact multiples
  float4 f = *(const float4*)(s + i);
  ushort4 o;
  o.x = f2bf(f.x); o.y = f2bf(f.y); o.z = f2bf(f.z); o.w = f2bf(f.w);
  *(ushort4*)(d + i) = o;
}

// ---------------- shared NT-GEMM main loop (m97 structure) ----------------
DEV void gemm_mainloop(const unsigned short* __restrict__ A, int Arows,
                       const unsigned short* __restrict__ Bw,
                       unsigned short* As, unsigned short* Bs,
                       int mbase, int nbase, f32x4 acc[4][4]) {
  const int tid  = threadIdx.x;
  const int lane = tid & 63;
  const int wave = tid >> 6;
  const int wm = wave & 1, wn = wave >> 1;
  const int l16 = lane & 15, quad = lane >> 4;

  for (int k0 = 0; k0 < DIMC; k0 += 64) {
#pragma unroll
    for (int i = 0; i < 4; ++i) {
      int c = i * 256 + tid;          // LDS chunk id 0..1023 (16B chunks)
      int row = c >> 3, cc = c & 7;
      int gc = (cc ^ (row & 7)) * 8;  // swizzled global chunk
      int ar = mbase + row; ar = ar < Arows ? ar : Arows - 1;  // M tail clamp
      async_cp16(A  + (size_t)ar * DIMC + k0 + gc, As + c * 8);
      async_cp16(Bw + (size_t)(nbase + row) * DIMC + k0 + gc, Bs + c * 8);
    }
    __syncthreads();
#pragma unroll
    for (int kk = 0; kk < 64; kk += 32) {
      const int cw = (kk >> 3) + quad;
      bf16x8 af[4], bfr[4];
#pragma unroll
      for (int mi = 0; mi < 4; ++mi) {
        int r = wm * 64 + mi * 16 + l16;
        af[mi] = *(const bf16x8*)(As + r * 64 + (cw ^ (r & 7)) * 8);
      }
#pragma unroll
      for (int ni = 0; ni < 4; ++ni) {
        int r = wn * 64 + ni * 16 + l16;
        bfr[ni] = *(const bf16x8*)(Bs + r * 64 + (cw ^ (r & 7)) * 8);
      }
#pragma unroll
      for (int mi = 0; mi < 4; ++mi)
#pragma unroll
        for (int ni = 0; ni < 4; ++ni)
          acc[mi][ni] = mfma16(af[mi], bfr[ni], acc[mi][ni]);
    }
    __syncthreads();
  }
}

// ---------------- QKV GEMM -> qkv bf16 [3][B][H][N][HD] ----------------
__global__ void __launch_bounds__(256) gemm_qkv(const unsigned short* __restrict__ A,
                                                const unsigned short* __restrict__ Bw,
                                                unsigned short* __restrict__ qkv,
                                                int gridM, int gridN) {
  __shared__ __align__(16) unsigned short As[128 * 64];
  __shared__ __align__(16) unsigned short Bs[128 * 64];
  const int tid = threadIdx.x, lane = tid & 63, wave = tid >> 6;
  const int wm = wave & 1, wn = wave >> 1;
  const int l16 = lane & 15, quad = lane >> 4;
  int mbase, nbase;
  swizzle_mn(blockIdx.x, gridM, gridN, mbase, nbase);

  f32x4 acc[4][4];
#pragma unroll
  for (int i = 0; i < 4; ++i)
#pragma unroll
    for (int j = 0; j < 4; ++j) acc[i][j] = {0.f, 0.f, 0.f, 0.f};

  gemm_mainloop(A, MTOK, Bw, As, Bs, mbase, nbase, acc);

  const int oc64  = nbase + wn * 64;            // 64-aligned -> uniform which/h
  const int which = oc64 / DIMC;
  const int h     = (oc64 % DIMC) / HDIM;
#pragma unroll
  for (int mi = 0; mi < 4; ++mi) {
    int t0 = mbase + wm * 64 + mi * 16 + quad * 4;
#pragma unroll
    for (int r = 0; r < 4; ++r) {
      int t = t0 + r;
      if (t < MTOK) {
        int b = t / NTOK, n = t - b * NTOK;
        size_t base = ((size_t)((which * NB + b) * NH + h) * NTOK + n) * HDIM;
#pragma unroll
        for (int ni = 0; ni < 4; ++ni)
          qkv[base + ni * 16 + l16] = f2bf(acc[mi][ni][r]);
      }
    }
  }
}

// ---------------- Proj GEMM + bias + residual (fp32 out) ----------------
__global__ void __launch_bounds__(256) gemm_proj(const unsigned short* __restrict__ A,
                                                 const unsigned short* __restrict__ Bw,
                                                 const float* __restrict__ bias,
                                                 const float* __restrict__ xres,
                                                 float* __restrict__ out,
                                                 int gridM, int gridN) {
  __shared__ __align__(16) unsigned short As[128 * 64];
  __shared__ __align__(16) unsigned short Bs[128 * 64];
  const int tid = threadIdx.x, lane = tid & 63, wave = tid >> 6;
  const int wm = wave & 1, wn = wave >> 1;
  const int l16 = lane & 15, quad = lane >> 4;
  int mbase, nbase;
  swizzle_mn(blockIdx.x, gridM, gridN, mbase, nbase);

  f32x4 acc[4][4];
#pragma unroll
  for (int i = 0; i < 4; ++i)
#pragma unroll
    for (int j = 0; j < 4; ++j) acc[i][j] = {0.f, 0.f, 0.f, 0.f};

  gemm_mainloop(A, MTOK, Bw, As, Bs, mbase, nbase, acc);

  const int oc = nbase + wn * 64;
#pragma unroll
  for (int mi = 0; mi < 4; ++mi) {
    int t0 = mbase + wm * 64 + mi * 16 + quad * 4;
#pragma unroll
    for (int r = 0; r < 4; ++r) {
      int t = t0 + r;
      if (t < MTOK) {
        size_t rowb = (size_t)t * DIMC;
#pragma unroll
        for (int ni = 0; ni < 4; ++ni) {
          int o = oc + ni * 16 + l16;
          out[rowb + o] = acc[mi][ni][r] + bias[o] + xres[rowb + o];
        }
      }
    }
  }
}

// ---------------- fused attention: 768 blocks x 1 head ----------------
// Per block: K staged via async DMA (XOR-swizzled, conflict-free b128 reads);
// V^T built via coalesced 128B row reads + bank-walking-stride ds_write_b128
// (VTS=232 u16 = 464B, NOT a multiple of 128B -- the R5 stride-448B layout
// caused ~32-way write conflicts). 2 blocks/CU co-resident (63.7KB LDS) so
// one block's staging overlaps the other's compute; no serial-head loop.
__global__ void __launch_bounds__(256, 2) attn_fused(const unsigned short* __restrict__ qkv,
                                                     const float* __restrict__ scale,
                                                     unsigned short* __restrict__ aout) {
  __shared__ __align__(16) unsigned short Ks[KROWS * 64];        // 25344 B
  __shared__ __align__(16) unsigned short Vt[HDIM * VTS];        // 29696 B
  __shared__ __align__(16) unsigned short Ob[4 * 16 * OBS];      //  8704 B
  // total 63744 B <= 64KB

  const int tid = threadIdx.x, lane = tid & 63, wave = tid >> 6;
  const int l16 = lane & 15, quad = lane >> 4;
  const int bh = blockIdx.x;
  const int b = bh / NH, h = bh - b * NH;

  const unsigned short* qg = qkv + (size_t)bh * (NTOK * HDIM);
  const unsigned short* kg = qkv + (size_t)(BH + bh) * (NTOK * HDIM);
  const unsigned short* vg = qkv + (size_t)(2 * BH + bh) * (NTOK * HDIM);
  const float sc = scale[h];

  // ---- stage K via DMA: rows 0..197 (1584 chunks of 16B) ----
#pragma unroll
  for (int i = 0; i < 7; ++i) {
    int c = i * 256 + tid;
    if (c < KROWS * 8) {
      int row = c >> 3, cc = c & 7;
      async_cp16(kg + (size_t)row * 64 + ((cc ^ (row & 7)) * 8), Ks + c * 8);
    }
  }
  // ---- build V^T: coalesced row reads + one b128 LDS write per pass ----
  {
    const int dcol = tid & 63;             // this thread's V column
    const int slab = tid >> 6;             // wave -> 8-row slab
#pragma unroll
    for (int p = 0; p < 7; ++p) {
      int n0 = p * 32 + slab * 8;
      union { unsigned short us[8]; bf16x8 v; } tr;
#pragma unroll
      for (int i = 0; i < 8; ++i) {
        int n = n0 + i; n = n > NTOK - 1 ? NTOK - 1 : n;   // clamp (masked)
        tr.us[i] = vg[(size_t)n * HDIM + dcol];            // 128B line/instr
      }
      *(bf16x8*)(Vt + dcol * VTS + n0) = tr.v;
    }
  }
  __syncthreads();   // drains DMA vmcnt + Vt lgkm

  // P-exchange lanes (R3-proven): B-frag P^T[k=quad*8+j][n=q=l16]
  const int srcA  = l16 + ((quad & 1) << 5);
  const int srcB  = srcA + 16;
  const int stsel = quad >> 1;
  unsigned short* ob = Ob + wave * (16 * OBS);

  for (int mt = wave; mt < 13; mt += 4) {   // Q 16-row tiles, round-robin
    int qr = mt * 16 + l16; if (qr > NTOK - 1) qr = NTOK - 1;
    bf16x8 qb0 = *(const bf16x8*)(qg + (size_t)qr * 64 + quad * 8);
    bf16x8 qb1 = *(const bf16x8*)(qg + (size_t)qr * 64 + 32 + quad * 8);
    const int mg = mt * 16 + l16;           // global Q row (diag mask)

    // ---- batched S^T = K.Q^T (26 MFMAs; jc=6,st=1 keys all masked) ----
    f32x4 s[7][2];
#pragma unroll
    for (int jc = 0; jc < 7; ++jc)
#pragma unroll
      for (int st = 0; st < 2; ++st) {
        if (jc == 6 && st == 1) { s[6][1] = {0.f, 0.f, 0.f, 0.f}; continue; }
        int jrow = (jc * 2 + st) * 16 + l16;
        jrow = jrow > NTOK ? NTOK : jrow;        // clamp to 197 (masked rows)
        const unsigned short* kr = Ks + jrow * 64;
        bf16x8 ka0 = *(const bf16x8*)(kr + (quad       ^ (jrow & 7)) * 8);
        bf16x8 ka1 = *(const bf16x8*)(kr + ((4 + quad) ^ (jrow & 7)) * 8);
        f32x4 t = {0.f, 0.f, 0.f, 0.f};
        t = mfma16(ka0, qb0, t);
        t = mfma16(ka1, qb1, t);
        s[jc][st] = t;
      }

    // ---- softmax over keys (row = l16): scale+mask, max, exp, sum ----
    float cmax = -1e30f;
#pragma unroll
    for (int jc = 0; jc < 7; ++jc)
#pragma unroll
      for (int st = 0; st < 2; ++st)
#pragma unroll
        for (int r = 0; r < 4; ++r) {
          int jg = jc * 32 + st * 16 + quad * 4 + r;
          float v = s[jc][st][r] * sc;
          v = (jg >= NTOK || jg == mg) ? -1e30f : v;   // select: NaN-safe
          s[jc][st][r] = v;
          cmax = fmaxf(cmax, v);
        }
    cmax = fmaxf(cmax, __shfl_xor(cmax, 16));
    cmax = fmaxf(cmax, __shfl_xor(cmax, 32));
    float psum = 0.f;
#pragma unroll
    for (int jc = 0; jc < 7; ++jc)
#pragma unroll
      for (int st = 0; st < 2; ++st)
#pragma unroll
        for (int r = 0; r < 4; ++r) {
          float e = __expf(s[jc][st][r] - cmax);
          psum += e;
          s[jc][st][r] = e;
        }
    psum += __shfl_xor(psum, 16);
    psum += __shfl_xor(psum, 32);
    const float inv = 1.0f / psum;

    // ---- PV: O^T = V^T.P^T; P^T B-frags via shfl, V^T b128 from LDS ----
    f32x4 oacc[4];
#pragma unroll
    for (int dt = 0; dt < 4; ++dt) oacc[dt] = {0.f, 0.f, 0.f, 0.f};

#pragma unroll
    for (int jc = 0; jc < 7; ++jc) {
      uint32_t u0 = pack_bf2(s[jc][0][0], s[jc][0][1]);
      uint32_t v0 = pack_bf2(s[jc][0][2], s[jc][0][3]);
      uint32_t u1 = pack_bf2(s[jc][1][0], s[jc][1][1]);
      uint32_t v1 = pack_bf2(s[jc][1][2], s[jc][1][3]);
      uint32_t au0 = (uint32_t)__shfl((int)u0, srcA);
      uint32_t av0 = (uint32_t)__shfl((int)v0, srcA);
      uint32_t au1 = (uint32_t)__shfl((int)u1, srcA);
      uint32_t av1 = (uint32_t)__shfl((int)v1, srcA);
      uint32_t bu0 = (uint32_t)__shfl((int)u0, srcB);
      uint32_t bv0 = (uint32_t)__shfl((int)v0, srcB);
      uint32_t bu1 = (uint32_t)__shfl((int)u1, srcB);
      uint32_t bv1 = (uint32_t)__shfl((int)v1, srcB);
      union { uint32_t u[4]; bf16x8 v; } pb;
      pb.u[0] = stsel ? au1 : au0;
      pb.u[1] = stsel ? av1 : av0;
      pb.u[2] = stsel ? bu1 : bu0;
      pb.u[3] = stsel ? bv1 : bv0;
#pragma unroll
      for (int dt = 0; dt < 4; ++dt) {
        bf16x8 va = *(const bf16x8*)(Vt + (dt * 16 + l16) * VTS +
                                     jc * 32 + quad * 8);
        oacc[dt] = mfma16(va, pb.v, oacc[dt]);
      }
    }

    // ---- O store via per-wave LDS bounce -> full 128B line stores ----
#pragma unroll
    for (int dt = 0; dt < 4; ++dt) {
      ushort4 pk;
      pk.x = f2bf(oacc[dt][0] * inv);
      pk.y = f2bf(oacc[dt][1] * inv);
      pk.z = f2bf(oacc[dt][2] * inv);
      pk.w = f2bf(oacc[dt][3] * inv);
      *(ushort4*)(ob + l16 * OBS + dt * 16 + quad * 4) = pk;
    }
    __asm__ __volatile__("s_waitcnt lgkmcnt(0)" ::: "memory");
#pragma unroll
    for (int rnd = 0; rnd < 4; ++rnd) {
      int q   = rnd * 4 + (lane >> 4);     // 0..15
      int o8  = lane & 15;                 // 8B unit within the 128B row
      uint2 d8 = *(const uint2*)(ob + q * OBS + o8 * 4);
      int qrow = mt * 16 + q;
      if (qrow < NTOK) {
        size_t obase = (size_t)(b * NTOK + qrow) * DIMC + h * HDIM;
        *(uint2*)(aout + obase + o8 * 4) = d8;   // 16 lanes = full 128B line
      }
    }
  }
}

// ---------------- launcher ----------------
extern "C" void kernel_launch(void* const* d_in, const int* in_sizes, int n_in,
                              void* d_out, int out_size, void* d_ws, size_t ws_size,
                              hipStream_t stream) {
  const float* x     = (const float*)d_in[0];
  const float* scale = (const float*)d_in[1];
  const float* wqkv  = (const float*)d_in[2];
  const float* wproj = (const float*)d_in[3];
  const float* bproj = (const float*)d_in[4];
  float* out = (float*)d_out;

  // ws layout (ushort), ~82.2 MB. attb aliases xb (dead after gemm_qkv;
  // proj residual reads fp32 x).
  unsigned short* xb   = (unsigned short*)d_ws;
  unsigned short* wqb  = xb  + (size_t)MTOK * DIMC;
  unsigned short* wpb  = wqb + (size_t)QKVO * DIMC;
  unsigned short* qkvb = wpb + (size_t)DIMC * DIMC;
  unsigned short* attb = xb;                          // alias

  cvt_all<<<CVT_B1 + CVT_B2 + CVT_B3, 256, 0, stream>>>(x, wqkv, wproj,
                                                        xb, wqb, wpb);

  const int gmM = (MTOK + 127) / 128;      // 99
  gemm_qkv<<<gmM * (QKVO / 128), 256, 0, stream>>>(xb, wqb, qkvb, gmM, QKVO / 128);
  attn_fused<<<BH, 256, 0, stream>>>(qkvb, scale, attb);
  gemm_proj<<<gmM * (DIMC / 128), 256, 0, stream>>>(attb, wpb, bproj, x, out,
                                                    gmM, DIMC / 128);
}